// Round 3
// baseline (359.303 us; speedup 1.0000x reference)
//
#include <hip/hip_runtime.h>
#include <hip/hip_fp16.h>

#define NEG_SLOPE 0.2f

// ---------------------------------------------------------------- CSR build

__global__ void count_k(const int* __restrict__ dst, int* __restrict__ cnt, int e) {
    int g = blockIdx.x * blockDim.x + threadIdx.x;
    if (g < e) atomicAdd(&cnt[dst[g]], 1);
}

__global__ void scan1(const int* __restrict__ cnt, int* __restrict__ offs,
                      int* __restrict__ partial, int n) {
    __shared__ int s[256];
    int tid = threadIdx.x;
    int g = blockIdx.x * 256 + tid;
    int v = (g < n) ? cnt[g] : 0;
    s[tid] = v;
    __syncthreads();
    for (int off = 1; off < 256; off <<= 1) {
        int t = (tid >= off) ? s[tid - off] : 0;
        __syncthreads();
        s[tid] += t;
        __syncthreads();
    }
    if (g < n) offs[g] = s[tid] - v;            // exclusive within block
    if (tid == 255) partial[blockIdx.x] = s[255];
}

__global__ void scan2(int* __restrict__ partial, int p) {
    __shared__ int s[256];
    int tid = threadIdx.x;
    int v = (tid < p) ? partial[tid] : 0;
    s[tid] = v;
    __syncthreads();
    for (int off = 1; off < 256; off <<= 1) {
        int t = (tid >= off) ? s[tid - off] : 0;
        __syncthreads();
        s[tid] += t;
        __syncthreads();
    }
    if (tid < p) partial[tid] = s[tid] - v;     // exclusive
}

__global__ void scan3(int* __restrict__ offs, const int* __restrict__ partial,
                      int n, int e) {
    int g = blockIdx.x * 256 + threadIdx.x;
    if (g < n) offs[g] += partial[blockIdx.x];
    if (g == 0) offs[n] = e;
}

__global__ void scatter_k(const int* __restrict__ src, const int* __restrict__ dst,
                          const int* __restrict__ offs, int* __restrict__ cursor,
                          int* __restrict__ csr_src, int e) {
    int g = blockIdx.x * blockDim.x + threadIdx.x;
    if (g < e) {
        int d = dst[g];
        int pos = atomicAdd(&cursor[d], 1);
        csr_src[offs[d] + pos] = src[g];
    }
}

// --------------------------------------------------- fused dual GEMM (fp32→fp16)
// C_l = A @ Wl + bl ; C_r = A @ Wr + br.  A:[N,128] fp32, W:[128,128] fp32.
// Outputs stored fp16 (consumed only by attn gather — halves gather bytes).

#define MB 64
#define KC 32

union Pack8h { __half2 h2[4]; float4 f4; };

__global__ __launch_bounds__(256, 2) void gemm_dual(
    const float* __restrict__ A,
    const float* __restrict__ Wl, const float* __restrict__ bl,
    const float* __restrict__ Wr, const float* __restrict__ br,
    __half* __restrict__ outl, __half* __restrict__ outr)
{
    __shared__ float At[KC][MB + 4];     // transposed A chunk
    __shared__ float Wls[KC][128];
    __shared__ float Wrs[KC][128];

    const int tid = threadIdx.x;
    const int base = blockIdx.x * MB;
    const int r0 = (tid >> 4) << 2;      // 0..60
    const int c0 = (tid & 15) << 3;      // 0..120

    float accl[4][8], accr[4][8];
#pragma unroll
    for (int i = 0; i < 4; ++i)
#pragma unroll
        for (int j = 0; j < 8; ++j) { accl[i][j] = 0.f; accr[i][j] = 0.f; }

    for (int kc = 0; kc < 128; kc += KC) {
#pragma unroll
        for (int it = 0; it < 2; ++it) {
            int f = tid + it * 256;
            int row = f >> 3, kq = (f & 7) << 2;
            const float4 v = *(const float4*)&A[(size_t)(base + row) * 128 + kc + kq];
            At[kq + 0][row] = v.x; At[kq + 1][row] = v.y;
            At[kq + 2][row] = v.z; At[kq + 3][row] = v.w;
        }
#pragma unroll
        for (int it = 0; it < 4; ++it) {
            int f = tid + it * 256;
            int kk = f >> 5, cq = (f & 31) << 2;
            *(float4*)&Wls[kk][cq] = *(const float4*)&Wl[(size_t)(kc + kk) * 128 + cq];
            *(float4*)&Wrs[kk][cq] = *(const float4*)&Wr[(size_t)(kc + kk) * 128 + cq];
        }
        __syncthreads();

#pragma unroll
        for (int kk = 0; kk < KC; ++kk) {
            const float4 a  = *(const float4*)&At[kk][r0];
            const float4 l0 = *(const float4*)&Wls[kk][c0];
            const float4 l1 = *(const float4*)&Wls[kk][c0 + 4];
            const float4 q0 = *(const float4*)&Wrs[kk][c0];
            const float4 q1 = *(const float4*)&Wrs[kk][c0 + 4];
            const float av[4] = {a.x, a.y, a.z, a.w};
            const float wl[8] = {l0.x, l0.y, l0.z, l0.w, l1.x, l1.y, l1.z, l1.w};
            const float wr[8] = {q0.x, q0.y, q0.z, q0.w, q1.x, q1.y, q1.z, q1.w};
#pragma unroll
            for (int i = 0; i < 4; ++i)
#pragma unroll
                for (int j = 0; j < 8; ++j) {
                    accl[i][j] = fmaf(av[i], wl[j], accl[i][j]);
                    accr[i][j] = fmaf(av[i], wr[j], accr[i][j]);
                }
        }
        __syncthreads();
    }

    const float4 bl0 = *(const float4*)&bl[c0];
    const float4 bl1 = *(const float4*)&bl[c0 + 4];
    const float4 br0 = *(const float4*)&br[c0];
    const float4 br1 = *(const float4*)&br[c0 + 4];
#pragma unroll
    for (int i = 0; i < 4; ++i) {
        size_t row = (size_t)(base + r0 + i) * 128;
        Pack8h p;
        p.h2[0] = __floats2half2_rn(accl[i][0] + bl0.x, accl[i][1] + bl0.y);
        p.h2[1] = __floats2half2_rn(accl[i][2] + bl0.z, accl[i][3] + bl0.w);
        p.h2[2] = __floats2half2_rn(accl[i][4] + bl1.x, accl[i][5] + bl1.y);
        p.h2[3] = __floats2half2_rn(accl[i][6] + bl1.z, accl[i][7] + bl1.w);
        *(float4*)&outl[row + c0] = p.f4;
        p.h2[0] = __floats2half2_rn(accr[i][0] + br0.x, accr[i][1] + br0.y);
        p.h2[1] = __floats2half2_rn(accr[i][2] + br0.z, accr[i][3] + br0.w);
        p.h2[2] = __floats2half2_rn(accr[i][4] + br1.x, accr[i][5] + br1.y);
        p.h2[3] = __floats2half2_rn(accr[i][6] + br1.z, accr[i][7] + br1.w);
        *(float4*)&outr[row + c0] = p.f4;
    }
}

// -------------------------------------- per-node online-softmax aggregation
// One wave per node; lane owns 2 of 128 dims (fp16 gather, fp32 math).
// 8-edge unroll: 8 gathers + 8 shuffle chains in flight, one state merge
// per group (associative rescale — exact up to fp reordering).

__global__ __launch_bounds__(256) void attn_k(
    const __half* __restrict__ xl, const __half* __restrict__ xr,
    const int* __restrict__ offs, const int* __restrict__ csr_src,
    const float* __restrict__ att, const float* __restrict__ bias,
    float* __restrict__ out, int n)
{
    const int wid = (blockIdx.x * blockDim.x + threadIdx.x) >> 6;
    const int lane = threadIdx.x & 63;
    if (wid >= n) return;

    const int i0  = offs[wid];
    const int deg = offs[wid + 1] - i0;
    const float2 xrv = __half22float2(*(const __half2*)&xr[(size_t)wid * 128 + lane * 2]);
    const float2 av  = *(const float2*)&att[lane * 2];

    float m = -INFINITY, l = 0.f, acc0 = 0.f, acc1 = 0.f;

    for (int b = 0; b < deg; b += 64) {
        const int nb = min(64, deg - b);
        const int idx = (b + lane < deg) ? csr_src[i0 + b + lane] : 0;

        int e = 0;
        for (; e + 8 <= nb; e += 8) {
            int s[8];
#pragma unroll
            for (int j = 0; j < 8; ++j) s[j] = __shfl(idx, e + j);
            float2 xs[8];
#pragma unroll
            for (int j = 0; j < 8; ++j)
                xs[j] = __half22float2(*(const __half2*)&xl[(size_t)s[j] * 128 + lane * 2]);
            float p[8];
#pragma unroll
            for (int j = 0; j < 8; ++j) {
                float t0 = xs[j].x + xrv.x; t0 = t0 > 0.f ? t0 : NEG_SLOPE * t0;
                float t1 = xs[j].y + xrv.y; t1 = t1 > 0.f ? t1 : NEG_SLOPE * t1;
                p[j] = fmaf(t1, av.y, t0 * av.x);
            }
#pragma unroll
            for (int off = 32; off > 0; off >>= 1)
#pragma unroll
                for (int j = 0; j < 8; ++j) p[j] += __shfl_xor(p[j], off, 64);

            float mn = m;
#pragma unroll
            for (int j = 0; j < 8; ++j) mn = fmaxf(mn, p[j]);
            const float sc = __expf(m - mn);     // exp(-inf)=0 on first group
            float suml = 0.f, s0 = 0.f, s1 = 0.f;
#pragma unroll
            for (int j = 0; j < 8; ++j) {
                const float ex = __expf(p[j] - mn);
                suml += ex;
                s0 = fmaf(ex, xs[j].x, s0);
                s1 = fmaf(ex, xs[j].y, s1);
            }
            l    = fmaf(l,    sc, suml);
            acc0 = fmaf(acc0, sc, s0);
            acc1 = fmaf(acc1, sc, s1);
            m = mn;
        }

        for (; e < nb; ++e) {                     // tail (0-7 edges)
            const int s = __shfl(idx, e);
            const float2 xv = __half22float2(*(const __half2*)&xl[(size_t)s * 128 + lane * 2]);
            float t0 = xv.x + xrv.x; t0 = t0 > 0.f ? t0 : NEG_SLOPE * t0;
            float t1 = xv.y + xrv.y; t1 = t1 > 0.f ? t1 : NEG_SLOPE * t1;
            float part = fmaf(t1, av.y, t0 * av.x);
#pragma unroll
            for (int off = 32; off > 0; off >>= 1)
                part += __shfl_xor(part, off, 64);
            const float mn = fmaxf(m, part);
            const float sc = __expf(m - mn);
            const float p  = __expf(part - mn);
            l = fmaf(l, sc, p);
            acc0 = fmaf(acc0, sc, p * xv.x);
            acc1 = fmaf(acc1, sc, p * xv.y);
            m = mn;
        }
    }

    const float inv = 1.0f / fmaxf(l, 1e-16f);
    float o0 = fmaf(acc0, inv, bias[lane * 2]);
    float o1 = fmaf(acc1, inv, bias[lane * 2 + 1]);
    o0 = fmaxf(o0, 0.f);                     // ReLU after each layer
    o1 = fmaxf(o1, 0.f);
    *(float2*)&out[(size_t)wid * 128 + lane * 2] = make_float2(o0, o1);
}

// ---------------------------------------------------------------- launcher

extern "C" void kernel_launch(void* const* d_in, const int* in_sizes, int n_in,
                              void* d_out, int out_size, void* d_ws, size_t ws_size,
                              hipStream_t stream) {
    const float* x    = (const float*)d_in[0];
    const int*   ei   = (const int*)d_in[1];
    const float* Wl1  = (const float*)d_in[2];
    const float* bl1  = (const float*)d_in[3];
    const float* Wr1  = (const float*)d_in[4];
    const float* br1  = (const float*)d_in[5];
    const float* att1 = (const float*)d_in[6];
    const float* b1   = (const float*)d_in[7];
    const float* Wl2  = (const float*)d_in[8];
    const float* bl2  = (const float*)d_in[9];
    const float* Wr2  = (const float*)d_in[10];
    const float* br2  = (const float*)d_in[11];
    const float* att2 = (const float*)d_in[12];
    const float* b2   = (const float*)d_in[13];

    const int N = in_sizes[0] / 128;   // 40000
    const int E = in_sizes[1] / 2;     // 640000
    const int* srcp = ei;
    const int* dstp = ei + E;

    char* ws = (char*)d_ws;
    __half* xl     = (__half*)ws; ws += (size_t)N * 128 * 2;
    __half* xr     = (__half*)ws; ws += (size_t)N * 128 * 2;
    int*   csr_src = (int*)ws;    ws += (size_t)E * 4;
    int*   offs    = (int*)ws;    ws += ((size_t)N + 4) * 4;
    int*   cnt     = (int*)ws;    ws += (size_t)N * 4;
    int*   cursor  = (int*)ws;    ws += (size_t)N * 4;
    int*   partial = (int*)ws;
    float* h = (float*)d_out;          // layer-1 activations (rewritten by layer 2)

    const int scanBlocks = (N + 255) / 256;       // 157
    const int eBlocks = (E + 255) / 256;          // 2500

    hipMemsetAsync(cnt, 0, (size_t)N * 2 * 4, stream);   // cnt + cursor

    // ---- CSR by dst (shared by both layers) ----
    count_k<<<eBlocks, 256, 0, stream>>>(dstp, cnt, E);
    scan1<<<scanBlocks, 256, 0, stream>>>(cnt, offs, partial, N);
    scan2<<<1, 256, 0, stream>>>(partial, scanBlocks);
    scan3<<<scanBlocks, 256, 0, stream>>>(offs, partial, N, E);
    scatter_k<<<eBlocks, 256, 0, stream>>>(srcp, dstp, offs, cursor, csr_src, E);

    const int gemmBlocks = N / MB;                // 625
    const int attnBlocks = (N + 3) / 4;           // 10000 (4 waves/block)

    // ---- layer 1 ----
    gemm_dual<<<gemmBlocks, 256, 0, stream>>>(x, Wl1, bl1, Wr1, br1, xl, xr);
    attn_k<<<attnBlocks, 256, 0, stream>>>(xl, xr, offs, csr_src, att1, b1, h, N);

    // ---- layer 2 ----
    gemm_dual<<<gemmBlocks, 256, 0, stream>>>(h, Wl2, bl2, Wr2, br2, xl, xr);
    attn_k<<<attnBlocks, 256, 0, stream>>>(xl, xr, offs, csr_src, att2, b2,
                                           (float*)d_out, N);
}

// Round 4
// 317.608 us; speedup vs baseline: 1.1313x; 1.1313x over previous
//
#include <hip/hip_runtime.h>
#include <hip/hip_fp16.h>

#define NEG_SLOPE 0.2f
#define NEG_BIG   -1e30f

// ---------------------------------------------------------------- CSR build

__global__ void count_k(const int* __restrict__ dst, int* __restrict__ cnt, int e) {
    int g = blockIdx.x * blockDim.x + threadIdx.x;
    if (g < e) atomicAdd(&cnt[dst[g]], 1);
}

__global__ void scan1(const int* __restrict__ cnt, int* __restrict__ offs,
                      int* __restrict__ partial, int n) {
    __shared__ int s[256];
    int tid = threadIdx.x;
    int g = blockIdx.x * 256 + tid;
    int v = (g < n) ? cnt[g] : 0;
    s[tid] = v;
    __syncthreads();
    for (int off = 1; off < 256; off <<= 1) {
        int t = (tid >= off) ? s[tid - off] : 0;
        __syncthreads();
        s[tid] += t;
        __syncthreads();
    }
    if (g < n) offs[g] = s[tid] - v;            // exclusive within block
    if (tid == 255) partial[blockIdx.x] = s[255];
}

__global__ void scan2(int* __restrict__ partial, int p) {
    __shared__ int s[256];
    int tid = threadIdx.x;
    int v = (tid < p) ? partial[tid] : 0;
    s[tid] = v;
    __syncthreads();
    for (int off = 1; off < 256; off <<= 1) {
        int t = (tid >= off) ? s[tid - off] : 0;
        __syncthreads();
        s[tid] += t;
        __syncthreads();
    }
    if (tid < p) partial[tid] = s[tid] - v;     // exclusive
}

__global__ void scan3(int* __restrict__ offs, const int* __restrict__ partial,
                      int n, int e) {
    int g = blockIdx.x * 256 + threadIdx.x;
    if (g < n) offs[g] += partial[blockIdx.x];
    if (g == 0) offs[n] = e;
}

__global__ void scatter_k(const int* __restrict__ src, const int* __restrict__ dst,
                          const int* __restrict__ offs, int* __restrict__ cursor,
                          int* __restrict__ csr_src, int e) {
    int g = blockIdx.x * blockDim.x + threadIdx.x;
    if (g < e) {
        int d = dst[g];
        int pos = atomicAdd(&cursor[d], 1);
        csr_src[offs[d] + pos] = src[g];
    }
}

// --------------------------------------------------- fused dual GEMM (fp32→fp16)

#define MB 64
#define KC 32

union Pack8h { __half2 h2[4]; float4 f4; };

__global__ __launch_bounds__(256, 2) void gemm_dual(
    const float* __restrict__ A,
    const float* __restrict__ Wl, const float* __restrict__ bl,
    const float* __restrict__ Wr, const float* __restrict__ br,
    __half* __restrict__ outl, __half* __restrict__ outr)
{
    __shared__ float At[KC][MB + 4];     // transposed A chunk
    __shared__ float Wls[KC][128];
    __shared__ float Wrs[KC][128];

    const int tid = threadIdx.x;
    const int base = blockIdx.x * MB;
    const int r0 = (tid >> 4) << 2;      // 0..60
    const int c0 = (tid & 15) << 3;      // 0..120

    float accl[4][8], accr[4][8];
#pragma unroll
    for (int i = 0; i < 4; ++i)
#pragma unroll
        for (int j = 0; j < 8; ++j) { accl[i][j] = 0.f; accr[i][j] = 0.f; }

    for (int kc = 0; kc < 128; kc += KC) {
#pragma unroll
        for (int it = 0; it < 2; ++it) {
            int f = tid + it * 256;
            int row = f >> 3, kq = (f & 7) << 2;
            const float4 v = *(const float4*)&A[(size_t)(base + row) * 128 + kc + kq];
            At[kq + 0][row] = v.x; At[kq + 1][row] = v.y;
            At[kq + 2][row] = v.z; At[kq + 3][row] = v.w;
        }
#pragma unroll
        for (int it = 0; it < 4; ++it) {
            int f = tid + it * 256;
            int kk = f >> 5, cq = (f & 31) << 2;
            *(float4*)&Wls[kk][cq] = *(const float4*)&Wl[(size_t)(kc + kk) * 128 + cq];
            *(float4*)&Wrs[kk][cq] = *(const float4*)&Wr[(size_t)(kc + kk) * 128 + cq];
        }
        __syncthreads();

#pragma unroll
        for (int kk = 0; kk < KC; ++kk) {
            const float4 a  = *(const float4*)&At[kk][r0];
            const float4 l0 = *(const float4*)&Wls[kk][c0];
            const float4 l1 = *(const float4*)&Wls[kk][c0 + 4];
            const float4 q0 = *(const float4*)&Wrs[kk][c0];
            const float4 q1 = *(const float4*)&Wrs[kk][c0 + 4];
            const float av[4] = {a.x, a.y, a.z, a.w};
            const float wl[8] = {l0.x, l0.y, l0.z, l0.w, l1.x, l1.y, l1.z, l1.w};
            const float wr[8] = {q0.x, q0.y, q0.z, q0.w, q1.x, q1.y, q1.z, q1.w};
#pragma unroll
            for (int i = 0; i < 4; ++i)
#pragma unroll
                for (int j = 0; j < 8; ++j) {
                    accl[i][j] = fmaf(av[i], wl[j], accl[i][j]);
                    accr[i][j] = fmaf(av[i], wr[j], accr[i][j]);
                }
        }
        __syncthreads();
    }

    const float4 bl0 = *(const float4*)&bl[c0];
    const float4 bl1 = *(const float4*)&bl[c0 + 4];
    const float4 br0 = *(const float4*)&br[c0];
    const float4 br1 = *(const float4*)&br[c0 + 4];
#pragma unroll
    for (int i = 0; i < 4; ++i) {
        size_t row = (size_t)(base + r0 + i) * 128;
        Pack8h p;
        p.h2[0] = __floats2half2_rn(accl[i][0] + bl0.x, accl[i][1] + bl0.y);
        p.h2[1] = __floats2half2_rn(accl[i][2] + bl0.z, accl[i][3] + bl0.w);
        p.h2[2] = __floats2half2_rn(accl[i][4] + bl1.x, accl[i][5] + bl1.y);
        p.h2[3] = __floats2half2_rn(accl[i][6] + bl1.z, accl[i][7] + bl1.w);
        *(float4*)&outl[row + c0] = p.f4;
        p.h2[0] = __floats2half2_rn(accr[i][0] + br0.x, accr[i][1] + br0.y);
        p.h2[1] = __floats2half2_rn(accr[i][2] + br0.z, accr[i][3] + br0.w);
        p.h2[2] = __floats2half2_rn(accr[i][4] + br1.x, accr[i][5] + br1.y);
        p.h2[3] = __floats2half2_rn(accr[i][6] + br1.z, accr[i][7] + br1.w);
        *(float4*)&outr[row + c0] = p.f4;
    }
}

// -------------------------------------- per-node online-softmax aggregation
// One wave per node; 16 lanes per edge (4 edges in flight per wave).
// lane = (g,t): g=lane>>4 edge-group, t=lane&15 owns dims t*8..t*8+7.
// Dot reduce = 4 shuffles per 4 edges (1 DS op/edge). Per-group online
// softmax state; groups merged once per node (exact up to fp reorder).
// Invalid slots use -1e30 sentinel; zero-valid groups annihilate at merge.

__device__ __forceinline__ void cvt8(float4 rv, float* o) {
    const __half2* h = (const __half2*)&rv;
#pragma unroll
    for (int k = 0; k < 4; ++k) {
        float2 f = __half22float2(h[k]);
        o[2 * k] = f.x; o[2 * k + 1] = f.y;
    }
}

__global__ __launch_bounds__(256) void attn_k(
    const __half* __restrict__ xl, const __half* __restrict__ xr,
    const int* __restrict__ offs, const int* __restrict__ csr_src,
    const float* __restrict__ att, const float* __restrict__ bias,
    float* __restrict__ out, int n)
{
    const int wid = (blockIdx.x * blockDim.x + threadIdx.x) >> 6;
    const int lane = threadIdx.x & 63;
    if (wid >= n) return;
    const int g = lane >> 4;          // edge group 0..3
    const int t = lane & 15;          // dim slot: dims t*8 .. t*8+7

    const int i0  = offs[wid];
    const int deg = offs[wid + 1] - i0;

    float xrv[8], av[8];
    cvt8(*(const float4*)&xr[(size_t)wid * 128 + t * 8], xrv);
    {
        float4 a0 = *(const float4*)&att[t * 8];
        float4 a1 = *(const float4*)&att[t * 8 + 4];
        av[0]=a0.x; av[1]=a0.y; av[2]=a0.z; av[3]=a0.w;
        av[4]=a1.x; av[5]=a1.y; av[6]=a1.z; av[7]=a1.w;
    }

    float m = NEG_BIG, l = 0.f, acc[8];
#pragma unroll
    for (int k = 0; k < 8; ++k) acc[k] = 0.f;

    for (int b = 0; b < deg; b += 64) {
        const int nb = min(64, deg - b);
        const int idx = (b + lane < deg) ? csr_src[i0 + b + lane] : 0;

        int e = 0;
        // 8-edge unroll: all slots valid (e+4+g <= e+7 < nb)
        for (; e + 8 <= nb; e += 8) {
            const int s0 = __shfl(idx, e + g);
            const int s1 = __shfl(idx, e + 4 + g);
            const float4 r0 = *(const float4*)&xl[(size_t)s0 * 128 + t * 8];
            const float4 r1 = *(const float4*)&xl[(size_t)s1 * 128 + t * 8];
            float xv0[8], xv1[8];
            cvt8(r0, xv0); cvt8(r1, xv1);

            float p0 = 0.f, p1 = 0.f;
#pragma unroll
            for (int k = 0; k < 8; ++k) {
                float z0 = xv0[k] + xrv[k];
                float z1 = xv1[k] + xrv[k];
                float u0 = fmaf(0.4f, fabsf(z0), 0.6f * z0);   // leaky_relu(z,0.2)
                float u1 = fmaf(0.4f, fabsf(z1), 0.6f * z1);
                p0 = fmaf(u0, av[k], p0);
                p1 = fmaf(u1, av[k], p1);
            }
#pragma unroll
            for (int off = 1; off <= 8; off <<= 1) {
                p0 += __shfl_xor(p0, off, 64);
                p1 += __shfl_xor(p1, off, 64);
            }

            const float mn = fmaxf(fmaxf(p0, p1), m);
            const float sc = __expf(m - mn);        // m=-1e30 -> 0
            const float e0 = __expf(p0 - mn);
            const float e1 = __expf(p1 - mn);
            l = fmaf(l, sc, e0 + e1);
#pragma unroll
            for (int k = 0; k < 8; ++k)
                acc[k] = fmaf(acc[k], sc, fmaf(e0, xv0[k], e1 * xv1[k]));
            m = mn;
        }

        // tail: 4 edges per step with validity mask
        for (; e < nb; e += 4) {
            const int pos = e + g;                   // <= 63
            const bool valid = pos < nb;
            const int s0 = __shfl(idx, pos);
            const float4 r0 = *(const float4*)&xl[(size_t)(valid ? s0 : 0) * 128 + t * 8];
            float xv0[8];
            cvt8(r0, xv0);
            float p0 = 0.f;
#pragma unroll
            for (int k = 0; k < 8; ++k) {
                float z0 = xv0[k] + xrv[k];
                float u0 = fmaf(0.4f, fabsf(z0), 0.6f * z0);
                p0 = fmaf(u0, av[k], p0);
            }
#pragma unroll
            for (int off = 1; off <= 8; off <<= 1)
                p0 += __shfl_xor(p0, off, 64);
            if (!valid) p0 = NEG_BIG;

            const float mn = fmaxf(p0, m);
            const float sc = __expf(m - mn);
            const float e0 = __expf(p0 - mn);        // invalid -> exp(-huge)=0 once m finite
            l = fmaf(l, sc, e0);
#pragma unroll
            for (int k = 0; k < 8; ++k)
                acc[k] = fmaf(acc[k], sc, e0 * xv0[k]);
            m = mn;
        }
    }

    // merge the 4 group states (butterfly over offsets 16, 32)
#pragma unroll
    for (int off = 16; off <= 32; off <<= 1) {
        const float mo = __shfl_xor(m, off, 64);
        const float lo = __shfl_xor(l, off, 64);
        float ao[8];
#pragma unroll
        for (int k = 0; k < 8; ++k) ao[k] = __shfl_xor(acc[k], off, 64);
        const float mn = fmaxf(m, mo);
        const float sa = __expf(m - mn);             // garbage groups: exp(-1e30-mn)=0
        const float sb = __expf(mo - mn);
        l = l * sa + lo * sb;
#pragma unroll
        for (int k = 0; k < 8; ++k) acc[k] = acc[k] * sa + ao[k] * sb;
        m = mn;
    }

    if (g == 0) {
        const float inv = 1.0f / fmaxf(l, 1e-16f);
        float o[8];
        const float4 b0 = *(const float4*)&bias[t * 8];
        const float4 b1 = *(const float4*)&bias[t * 8 + 4];
        const float bb[8] = {b0.x, b0.y, b0.z, b0.w, b1.x, b1.y, b1.z, b1.w};
#pragma unroll
        for (int k = 0; k < 8; ++k)
            o[k] = fmaxf(fmaf(acc[k], inv, bb[k]), 0.f);
        float* orow = &out[(size_t)wid * 128 + t * 8];
        *(float4*)&orow[0] = make_float4(o[0], o[1], o[2], o[3]);
        *(float4*)&orow[4] = make_float4(o[4], o[5], o[6], o[7]);
    }
}

// ---------------------------------------------------------------- launcher

extern "C" void kernel_launch(void* const* d_in, const int* in_sizes, int n_in,
                              void* d_out, int out_size, void* d_ws, size_t ws_size,
                              hipStream_t stream) {
    const float* x    = (const float*)d_in[0];
    const int*   ei   = (const int*)d_in[1];
    const float* Wl1  = (const float*)d_in[2];
    const float* bl1  = (const float*)d_in[3];
    const float* Wr1  = (const float*)d_in[4];
    const float* br1  = (const float*)d_in[5];
    const float* att1 = (const float*)d_in[6];
    const float* b1   = (const float*)d_in[7];
    const float* Wl2  = (const float*)d_in[8];
    const float* bl2  = (const float*)d_in[9];
    const float* Wr2  = (const float*)d_in[10];
    const float* br2  = (const float*)d_in[11];
    const float* att2 = (const float*)d_in[12];
    const float* b2   = (const float*)d_in[13];

    const int N = in_sizes[0] / 128;   // 40000
    const int E = in_sizes[1] / 2;     // 640000
    const int* srcp = ei;
    const int* dstp = ei + E;

    char* ws = (char*)d_ws;
    __half* xl     = (__half*)ws; ws += (size_t)N * 128 * 2;
    __half* xr     = (__half*)ws; ws += (size_t)N * 128 * 2;
    int*   csr_src = (int*)ws;    ws += (size_t)E * 4;
    int*   offs    = (int*)ws;    ws += ((size_t)N + 4) * 4;
    int*   cnt     = (int*)ws;    ws += (size_t)N * 4;
    int*   cursor  = (int*)ws;    ws += (size_t)N * 4;
    int*   partial = (int*)ws;
    float* h = (float*)d_out;          // layer-1 activations (rewritten by layer 2)

    const int scanBlocks = (N + 255) / 256;       // 157
    const int eBlocks = (E + 255) / 256;          // 2500

    hipMemsetAsync(cnt, 0, (size_t)N * 2 * 4, stream);   // cnt + cursor

    // ---- CSR by dst (shared by both layers) ----
    count_k<<<eBlocks, 256, 0, stream>>>(dstp, cnt, E);
    scan1<<<scanBlocks, 256, 0, stream>>>(cnt, offs, partial, N);
    scan2<<<1, 256, 0, stream>>>(partial, scanBlocks);
    scan3<<<scanBlocks, 256, 0, stream>>>(offs, partial, N, E);
    scatter_k<<<eBlocks, 256, 0, stream>>>(srcp, dstp, offs, cursor, csr_src, E);

    const int gemmBlocks = N / MB;                // 625
    const int attnBlocks = (N + 3) / 4;           // 10000 (4 waves/block)

    // ---- layer 1 ----
    gemm_dual<<<gemmBlocks, 256, 0, stream>>>(x, Wl1, bl1, Wr1, br1, xl, xr);
    attn_k<<<attnBlocks, 256, 0, stream>>>(xl, xr, offs, csr_src, att1, b1, h, N);

    // ---- layer 2 ----
    gemm_dual<<<gemmBlocks, 256, 0, stream>>>(h, Wl2, bl2, Wr2, br2, xl, xr);
    attn_k<<<attnBlocks, 256, 0, stream>>>(xl, xr, offs, csr_src, att2, b2,
                                           (float*)d_out, N);
}

// Round 5
// 306.891 us; speedup vs baseline: 1.1708x; 1.0349x over previous
//
#include <hip/hip_runtime.h>
#include <hip/hip_fp16.h>

#define NEG_SLOPE 0.2f
#define NEG_BIG   -1e30f

typedef _Float16 f16x8 __attribute__((ext_vector_type(8)));
typedef float    f32x4 __attribute__((ext_vector_type(4)));
union H8 { f16x8 h8; float4 f4; };

// ---------------------------------------------------------------- CSR build

__global__ void count_k(const int* __restrict__ dst, int* __restrict__ cnt, int e) {
    int g = blockIdx.x * blockDim.x + threadIdx.x;
    if (g < e) atomicAdd(&cnt[dst[g]], 1);
}

__global__ void scan1(const int* __restrict__ cnt, int* __restrict__ offs,
                      int* __restrict__ partial, int n) {
    __shared__ int s[256];
    int tid = threadIdx.x;
    int g = blockIdx.x * 256 + tid;
    int v = (g < n) ? cnt[g] : 0;
    s[tid] = v;
    __syncthreads();
    for (int off = 1; off < 256; off <<= 1) {
        int t = (tid >= off) ? s[tid - off] : 0;
        __syncthreads();
        s[tid] += t;
        __syncthreads();
    }
    if (g < n) offs[g] = s[tid] - v;            // exclusive within block
    if (tid == 255) partial[blockIdx.x] = s[255];
}

__global__ void scan2(int* __restrict__ partial, int p) {
    __shared__ int s[256];
    int tid = threadIdx.x;
    int v = (tid < p) ? partial[tid] : 0;
    s[tid] = v;
    __syncthreads();
    for (int off = 1; off < 256; off <<= 1) {
        int t = (tid >= off) ? s[tid - off] : 0;
        __syncthreads();
        s[tid] += t;
        __syncthreads();
    }
    if (tid < p) partial[tid] = s[tid] - v;     // exclusive
}

__global__ void scan3(int* __restrict__ offs, const int* __restrict__ partial,
                      int n, int e) {
    int g = blockIdx.x * 256 + threadIdx.x;
    if (g < n) offs[g] += partial[blockIdx.x];
    if (g == 0) offs[n] = e;
}

__global__ void scatter_k(const int* __restrict__ src, const int* __restrict__ dst,
                          const int* __restrict__ offs, int* __restrict__ cursor,
                          int* __restrict__ csr_src, int e) {
    int g = blockIdx.x * blockDim.x + threadIdx.x;
    if (g < e) {
        int d = dst[g];
        int pos = atomicAdd(&cursor[d], 1);
        csr_src[offs[d] + pos] = src[g];
    }
}

// ------------------------------------------- weight prep: fp32 [K][N] -> fp16 [N][K]

__global__ void wprep(const float* __restrict__ W, __half* __restrict__ Wt) {
    int idx = blockIdx.x * 256 + threadIdx.x;    // 16384 per matrix
    int n = idx & 127, k = idx >> 7;
    Wt[(size_t)n * 128 + k] = __float2half(W[(size_t)k * 128 + n]);
}

// ------------------------------------------- MFMA dual GEMM (fp32 A -> fp16 out)
// One wave per 16-row strip. Operand swap: D = Wt_tile(A-op) x A^T_tile(B-op)
// => lane holds out[m=lane&15][c*16 + quad*4 + r] : 4 consecutive cols -> 8B store.
// No LDS, no barriers. W fragments re-read from L2 (128 KB resident).

__global__ __launch_bounds__(256) void gemm_mfma(
    const float* __restrict__ A,
    const __half* __restrict__ WtL, const __half* __restrict__ WtR,
    const float* __restrict__ bl, const float* __restrict__ br,
    __half* __restrict__ outl, __half* __restrict__ outr, int nstrips)
{
    const int wid = (blockIdx.x * blockDim.x + threadIdx.x) >> 6;
    if (wid >= nstrips) return;
    const int lane = threadIdx.x & 63;
    const int mrow = lane & 15;
    const int quad = lane >> 4;
    const int base = wid * 16;

    // A fragments (B-operand role): lane holds A[base+mrow][kc*32 + quad*8 + j]
    f16x8 afrag[4];
    const float* arow = &A[(size_t)(base + mrow) * 128 + quad * 8];
#pragma unroll
    for (int kc = 0; kc < 4; ++kc) {
        const float4 f0 = *(const float4*)&arow[kc * 32];
        const float4 f1 = *(const float4*)&arow[kc * 32 + 4];
        f16x8 h;
        h[0] = (_Float16)f0.x; h[1] = (_Float16)f0.y;
        h[2] = (_Float16)f0.z; h[3] = (_Float16)f0.w;
        h[4] = (_Float16)f1.x; h[5] = (_Float16)f1.y;
        h[6] = (_Float16)f1.z; h[7] = (_Float16)f1.w;
        afrag[kc] = h;
    }

    const size_t orow = (size_t)(base + mrow) * 128;

#pragma unroll
    for (int c = 0; c < 8; ++c) {
        const size_t wof = (size_t)(c * 16 + mrow) * 128 + quad * 8;
        // ---- L ----
        {
            H8 w0, w1, w2, w3;
            w0.f4 = *(const float4*)&WtL[wof +  0];
            w1.f4 = *(const float4*)&WtL[wof + 32];
            w2.f4 = *(const float4*)&WtL[wof + 64];
            w3.f4 = *(const float4*)&WtL[wof + 96];
            f32x4 acc = {0.f, 0.f, 0.f, 0.f};
            acc = __builtin_amdgcn_mfma_f32_16x16x32_f16(w0.h8, afrag[0], acc, 0, 0, 0);
            acc = __builtin_amdgcn_mfma_f32_16x16x32_f16(w1.h8, afrag[1], acc, 0, 0, 0);
            acc = __builtin_amdgcn_mfma_f32_16x16x32_f16(w2.h8, afrag[2], acc, 0, 0, 0);
            acc = __builtin_amdgcn_mfma_f32_16x16x32_f16(w3.h8, afrag[3], acc, 0, 0, 0);
            const float4 bv = *(const float4*)&bl[c * 16 + quad * 4];
            union { __half2 h2[2]; float2 f2; } o;
            o.h2[0] = __floats2half2_rn(acc[0] + bv.x, acc[1] + bv.y);
            o.h2[1] = __floats2half2_rn(acc[2] + bv.z, acc[3] + bv.w);
            *(float2*)&outl[orow + c * 16 + quad * 4] = o.f2;
        }
        // ---- R ----
        {
            H8 w0, w1, w2, w3;
            w0.f4 = *(const float4*)&WtR[wof +  0];
            w1.f4 = *(const float4*)&WtR[wof + 32];
            w2.f4 = *(const float4*)&WtR[wof + 64];
            w3.f4 = *(const float4*)&WtR[wof + 96];
            f32x4 acc = {0.f, 0.f, 0.f, 0.f};
            acc = __builtin_amdgcn_mfma_f32_16x16x32_f16(w0.h8, afrag[0], acc, 0, 0, 0);
            acc = __builtin_amdgcn_mfma_f32_16x16x32_f16(w1.h8, afrag[1], acc, 0, 0, 0);
            acc = __builtin_amdgcn_mfma_f32_16x16x32_f16(w2.h8, afrag[2], acc, 0, 0, 0);
            acc = __builtin_amdgcn_mfma_f32_16x16x32_f16(w3.h8, afrag[3], acc, 0, 0, 0);
            const float4 bv = *(const float4*)&br[c * 16 + quad * 4];
            union { __half2 h2[2]; float2 f2; } o;
            o.h2[0] = __floats2half2_rn(acc[0] + bv.x, acc[1] + bv.y);
            o.h2[1] = __floats2half2_rn(acc[2] + bv.z, acc[3] + bv.w);
            *(float2*)&outr[orow + c * 16 + quad * 4] = o.f2;
        }
    }
}

// -------------------------------------- per-node online-softmax aggregation
// One wave per node; 16 lanes per edge (4 edges in flight per wave).

__device__ __forceinline__ void cvt8(float4 rv, float* o) {
    const __half2* h = (const __half2*)&rv;
#pragma unroll
    for (int k = 0; k < 4; ++k) {
        float2 f = __half22float2(h[k]);
        o[2 * k] = f.x; o[2 * k + 1] = f.y;
    }
}

__global__ __launch_bounds__(256) void attn_k(
    const __half* __restrict__ xl, const __half* __restrict__ xr,
    const int* __restrict__ offs, const int* __restrict__ csr_src,
    const float* __restrict__ att, const float* __restrict__ bias,
    float* __restrict__ out, int n)
{
    const int wid = (blockIdx.x * blockDim.x + threadIdx.x) >> 6;
    const int lane = threadIdx.x & 63;
    if (wid >= n) return;
    const int g = lane >> 4;          // edge group 0..3
    const int t = lane & 15;          // dim slot: dims t*8 .. t*8+7

    const int i0  = offs[wid];
    const int deg = offs[wid + 1] - i0;

    float xrv[8], av[8];
    cvt8(*(const float4*)&xr[(size_t)wid * 128 + t * 8], xrv);
    {
        float4 a0 = *(const float4*)&att[t * 8];
        float4 a1 = *(const float4*)&att[t * 8 + 4];
        av[0]=a0.x; av[1]=a0.y; av[2]=a0.z; av[3]=a0.w;
        av[4]=a1.x; av[5]=a1.y; av[6]=a1.z; av[7]=a1.w;
    }

    float m = NEG_BIG, l = 0.f, acc[8];
#pragma unroll
    for (int k = 0; k < 8; ++k) acc[k] = 0.f;

    for (int b = 0; b < deg; b += 64) {
        const int nb = min(64, deg - b);
        const int idx = (b + lane < deg) ? csr_src[i0 + b + lane] : 0;

        int e = 0;
        for (; e + 8 <= nb; e += 8) {
            const int s0 = __shfl(idx, e + g);
            const int s1 = __shfl(idx, e + 4 + g);
            const float4 r0 = *(const float4*)&xl[(size_t)s0 * 128 + t * 8];
            const float4 r1 = *(const float4*)&xl[(size_t)s1 * 128 + t * 8];
            float xv0[8], xv1[8];
            cvt8(r0, xv0); cvt8(r1, xv1);

            float p0 = 0.f, p1 = 0.f;
#pragma unroll
            for (int k = 0; k < 8; ++k) {
                float z0 = xv0[k] + xrv[k];
                float z1 = xv1[k] + xrv[k];
                float u0 = fmaf(0.4f, fabsf(z0), 0.6f * z0);   // leaky_relu(z,0.2)
                float u1 = fmaf(0.4f, fabsf(z1), 0.6f * z1);
                p0 = fmaf(u0, av[k], p0);
                p1 = fmaf(u1, av[k], p1);
            }
#pragma unroll
            for (int off = 1; off <= 8; off <<= 1) {
                p0 += __shfl_xor(p0, off, 64);
                p1 += __shfl_xor(p1, off, 64);
            }

            const float mn = fmaxf(fmaxf(p0, p1), m);
            const float sc = __expf(m - mn);        // m=-1e30 -> 0
            const float e0 = __expf(p0 - mn);
            const float e1 = __expf(p1 - mn);
            l = fmaf(l, sc, e0 + e1);
#pragma unroll
            for (int k = 0; k < 8; ++k)
                acc[k] = fmaf(acc[k], sc, fmaf(e0, xv0[k], e1 * xv1[k]));
            m = mn;
        }

        for (; e < nb; e += 4) {
            const int pos = e + g;                   // <= 63
            const bool valid = pos < nb;
            const int s0 = __shfl(idx, pos);
            const float4 r0 = *(const float4*)&xl[(size_t)(valid ? s0 : 0) * 128 + t * 8];
            float xv0[8];
            cvt8(r0, xv0);
            float p0 = 0.f;
#pragma unroll
            for (int k = 0; k < 8; ++k) {
                float z0 = xv0[k] + xrv[k];
                float u0 = fmaf(0.4f, fabsf(z0), 0.6f * z0);
                p0 = fmaf(u0, av[k], p0);
            }
#pragma unroll
            for (int off = 1; off <= 8; off <<= 1)
                p0 += __shfl_xor(p0, off, 64);
            if (!valid) p0 = NEG_BIG;

            const float mn = fmaxf(p0, m);
            const float sc = __expf(m - mn);
            const float e0 = __expf(p0 - mn);
            l = fmaf(l, sc, e0);
#pragma unroll
            for (int k = 0; k < 8; ++k)
                acc[k] = fmaf(acc[k], sc, e0 * xv0[k]);
            m = mn;
        }
    }

    // merge the 4 group states (butterfly over offsets 16, 32)
#pragma unroll
    for (int off = 16; off <= 32; off <<= 1) {
        const float mo = __shfl_xor(m, off, 64);
        const float lo = __shfl_xor(l, off, 64);
        float ao[8];
#pragma unroll
        for (int k = 0; k < 8; ++k) ao[k] = __shfl_xor(acc[k], off, 64);
        const float mn = fmaxf(m, mo);
        const float sa = __expf(m - mn);
        const float sb = __expf(mo - mn);
        l = l * sa + lo * sb;
#pragma unroll
        for (int k = 0; k < 8; ++k) acc[k] = acc[k] * sa + ao[k] * sb;
        m = mn;
    }

    if (g == 0) {
        const float inv = 1.0f / fmaxf(l, 1e-16f);
        float o[8];
        const float4 b0 = *(const float4*)&bias[t * 8];
        const float4 b1 = *(const float4*)&bias[t * 8 + 4];
        const float bb[8] = {b0.x, b0.y, b0.z, b0.w, b1.x, b1.y, b1.z, b1.w};
#pragma unroll
        for (int k = 0; k < 8; ++k)
            o[k] = fmaxf(fmaf(acc[k], inv, bb[k]), 0.f);
        float* orow = &out[(size_t)wid * 128 + t * 8];
        *(float4*)&orow[0] = make_float4(o[0], o[1], o[2], o[3]);
        *(float4*)&orow[4] = make_float4(o[4], o[5], o[6], o[7]);
    }
}

// ---------------------------------------------------------------- launcher

extern "C" void kernel_launch(void* const* d_in, const int* in_sizes, int n_in,
                              void* d_out, int out_size, void* d_ws, size_t ws_size,
                              hipStream_t stream) {
    const float* x    = (const float*)d_in[0];
    const int*   ei   = (const int*)d_in[1];
    const float* Wl1  = (const float*)d_in[2];
    const float* bl1  = (const float*)d_in[3];
    const float* Wr1  = (const float*)d_in[4];
    const float* br1  = (const float*)d_in[5];
    const float* att1 = (const float*)d_in[6];
    const float* b1   = (const float*)d_in[7];
    const float* Wl2  = (const float*)d_in[8];
    const float* bl2  = (const float*)d_in[9];
    const float* Wr2  = (const float*)d_in[10];
    const float* br2  = (const float*)d_in[11];
    const float* att2 = (const float*)d_in[12];
    const float* b2   = (const float*)d_in[13];

    const int N = in_sizes[0] / 128;   // 40000
    const int E = in_sizes[1] / 2;     // 640000
    const int* srcp = ei;
    const int* dstp = ei + E;

    char* ws = (char*)d_ws;
    __half* xl     = (__half*)ws; ws += (size_t)N * 128 * 2;
    __half* xr     = (__half*)ws; ws += (size_t)N * 128 * 2;
    int*   csr_src = (int*)ws;    ws += (size_t)E * 4;
    int*   offs    = (int*)ws;    ws += ((size_t)N + 4) * 4;
    int*   cnt     = (int*)ws;    ws += (size_t)N * 4;
    int*   cursor  = (int*)ws;    ws += (size_t)N * 4;
    int*   partial = (int*)ws;    ws += 1024;
    __half* Wt1l   = (__half*)ws; ws += 128 * 128 * 2;
    __half* Wt1r   = (__half*)ws; ws += 128 * 128 * 2;
    __half* Wt2l   = (__half*)ws; ws += 128 * 128 * 2;
    __half* Wt2r   = (__half*)ws; ws += 128 * 128 * 2;
    float* h = (float*)d_out;          // layer-1 activations (rewritten by layer 2)

    const int scanBlocks = (N + 255) / 256;       // 157
    const int eBlocks = (E + 255) / 256;          // 2500

    hipMemsetAsync(cnt, 0, (size_t)N * 2 * 4, stream);   // cnt + cursor

    // ---- weight prep (tiny, L2-resident thereafter) ----
    wprep<<<64, 256, 0, stream>>>(Wl1, Wt1l);
    wprep<<<64, 256, 0, stream>>>(Wr1, Wt1r);
    wprep<<<64, 256, 0, stream>>>(Wl2, Wt2l);
    wprep<<<64, 256, 0, stream>>>(Wr2, Wt2r);

    // ---- CSR by dst (shared by both layers) ----
    count_k<<<eBlocks, 256, 0, stream>>>(dstp, cnt, E);
    scan1<<<scanBlocks, 256, 0, stream>>>(cnt, offs, partial, N);
    scan2<<<1, 256, 0, stream>>>(partial, scanBlocks);
    scan3<<<scanBlocks, 256, 0, stream>>>(offs, partial, N, E);
    scatter_k<<<eBlocks, 256, 0, stream>>>(srcp, dstp, offs, cursor, csr_src, E);

    const int nstrips = N / 16;                   // 2500
    const int gemmBlocks = (nstrips + 3) / 4;     // 625 (4 waves/block)
    const int attnBlocks = (N + 3) / 4;           // 10000 (4 waves/block)

    // ---- layer 1 ----
    gemm_mfma<<<gemmBlocks, 256, 0, stream>>>(x, Wt1l, Wt1r, bl1, br1, xl, xr, nstrips);
    attn_k<<<attnBlocks, 256, 0, stream>>>(xl, xr, offs, csr_src, att1, b1, h, N);

    // ---- layer 2 ----
    gemm_mfma<<<gemmBlocks, 256, 0, stream>>>(h, Wt2l, Wt2r, bl2, br2, xl, xr, nstrips);
    attn_k<<<attnBlocks, 256, 0, stream>>>(xl, xr, offs, csr_src, att2, b2,
                                           (float*)d_out, N);
}

// Round 6
// 300.814 us; speedup vs baseline: 1.1944x; 1.0202x over previous
//
#include <hip/hip_runtime.h>
#include <hip/hip_fp16.h>

#define NEG_SLOPE 0.2f
#define NEG_BIG   -1e30f

typedef _Float16 f16x8 __attribute__((ext_vector_type(8)));
typedef _Float16 h2    __attribute__((ext_vector_type(2)));
typedef float    f32x4 __attribute__((ext_vector_type(4)));
union H8 { f16x8 h8; float4 f4; };
union H2x4 { float4 f4; h2 v[4]; _Float16 h[8]; };

static __device__ __forceinline__ h2 habs2(h2 x) {
    union { h2 v; unsigned u; } q; q.v = x; q.u &= 0x7FFF7FFFu; return q.v;
}

#if defined(__has_builtin)
#if __has_builtin(__builtin_amdgcn_fdot2)
#define FDOT2(a, b, c) __builtin_amdgcn_fdot2((a), (b), (c), false)
#endif
#endif
#ifndef FDOT2
#define FDOT2(a, b, c) fmaf((float)(a)[0], (float)(b)[0], \
                       fmaf((float)(a)[1], (float)(b)[1], (c)))
#endif

// ---------------------------------------------------------------- CSR build

__global__ void count_k(const int* __restrict__ dst, int* __restrict__ cnt, int e) {
    int g = blockIdx.x * blockDim.x + threadIdx.x;
    if (g < e) atomicAdd(&cnt[dst[g]], 1);
}

__global__ void scan1(const int* __restrict__ cnt, int* __restrict__ offs,
                      int* __restrict__ partial, int n) {
    __shared__ int s[256];
    int tid = threadIdx.x;
    int g = blockIdx.x * 256 + tid;
    int v = (g < n) ? ((cnt[g] + 7) & ~7) : 0;   // pad each segment to x8
    s[tid] = v;
    __syncthreads();
    for (int off = 1; off < 256; off <<= 1) {
        int t = (tid >= off) ? s[tid - off] : 0;
        __syncthreads();
        s[tid] += t;
        __syncthreads();
    }
    if (g < n) offs[g] = s[tid] - v;            // exclusive within block
    if (tid == 255) partial[blockIdx.x] = s[255];
}

__global__ void scan2(int* __restrict__ partial, int p) {
    __shared__ int s[256];
    int tid = threadIdx.x;
    int v = (tid < p) ? partial[tid] : 0;
    s[tid] = v;
    __syncthreads();
    for (int off = 1; off < 256; off <<= 1) {
        int t = (tid >= off) ? s[tid - off] : 0;
        __syncthreads();
        s[tid] += t;
        __syncthreads();
    }
    if (tid < p) partial[tid] = s[tid] - v;     // exclusive
}

__global__ void scan3(int* __restrict__ offs, const int* __restrict__ partial,
                      int n, int* __restrict__ total) {
    int g = blockIdx.x * 256 + threadIdx.x;
    if (g < n) offs[g] += partial[blockIdx.x];
    if (g == n - 1) offs[n] = offs[g] + 0;      // placeholder, fixed below
    if (g == n - 1) offs[n] = offs[g] ;         // overwritten by scan3b logic:
    // offs[n] must be offs[n-1] + padded cnt of last node; easier: store total
    if (g == n - 1) *total = 0;                 // unused
}

// (offs[n] handled in scan3b to avoid needing cnt here)
__global__ void scan3b(int* __restrict__ offs, const int* __restrict__ cnt, int n) {
    if (blockIdx.x == 0 && threadIdx.x == 0)
        offs[n] = offs[n - 1] + ((cnt[n - 1] + 7) & ~7);
}

__global__ void scatter_k(const int* __restrict__ src, const int* __restrict__ dst,
                          const int* __restrict__ offs, int* __restrict__ cursor,
                          int* __restrict__ csr_src, int e) {
    int g = blockIdx.x * blockDim.x + threadIdx.x;
    if (g < e) {
        int d = dst[g];
        int pos = atomicAdd(&cursor[d], 1);
        csr_src[offs[d] + pos] = src[g];
    }
}

// ------------------------------------------- weight prep: fp32 [K][N] -> fp16 [N][K]
// all four matrices in one launch (grid.y selects matrix)

__global__ void wprep4(const float* W0, const float* W1,
                       const float* W2, const float* W3,
                       __half* T0, __half* T1, __half* T2, __half* T3) {
    const float* W; __half* T;
    switch (blockIdx.y) {
        case 0: W = W0; T = T0; break;
        case 1: W = W1; T = T1; break;
        case 2: W = W2; T = T2; break;
        default: W = W3; T = T3; break;
    }
    int idx = blockIdx.x * 256 + threadIdx.x;    // 16384 per matrix
    int n = idx & 127, k = idx >> 7;
    T[(size_t)n * 128 + k] = __float2half(W[(size_t)k * 128 + n]);
}

// ------------------------------------------- MFMA dual GEMM (fp32 A -> fp16 out)

__global__ __launch_bounds__(256) void gemm_mfma(
    const float* __restrict__ A,
    const __half* __restrict__ WtL, const __half* __restrict__ WtR,
    const float* __restrict__ bl, const float* __restrict__ br,
    __half* __restrict__ outl, __half* __restrict__ outr, int nstrips)
{
    const int wid = (blockIdx.x * blockDim.x + threadIdx.x) >> 6;
    if (wid >= nstrips) return;
    const int lane = threadIdx.x & 63;
    const int mrow = lane & 15;
    const int quad = lane >> 4;
    const int base = wid * 16;

    f16x8 afrag[4];
    const float* arow = &A[(size_t)(base + mrow) * 128 + quad * 8];
#pragma unroll
    for (int kc = 0; kc < 4; ++kc) {
        const float4 f0 = *(const float4*)&arow[kc * 32];
        const float4 f1 = *(const float4*)&arow[kc * 32 + 4];
        f16x8 h;
        h[0] = (_Float16)f0.x; h[1] = (_Float16)f0.y;
        h[2] = (_Float16)f0.z; h[3] = (_Float16)f0.w;
        h[4] = (_Float16)f1.x; h[5] = (_Float16)f1.y;
        h[6] = (_Float16)f1.z; h[7] = (_Float16)f1.w;
        afrag[kc] = h;
    }

    const size_t orow = (size_t)(base + mrow) * 128;

#pragma unroll
    for (int c = 0; c < 8; ++c) {
        const size_t wof = (size_t)(c * 16 + mrow) * 128 + quad * 8;
        {
            H8 w0, w1, w2, w3;
            w0.f4 = *(const float4*)&WtL[wof +  0];
            w1.f4 = *(const float4*)&WtL[wof + 32];
            w2.f4 = *(const float4*)&WtL[wof + 64];
            w3.f4 = *(const float4*)&WtL[wof + 96];
            f32x4 acc = {0.f, 0.f, 0.f, 0.f};
            acc = __builtin_amdgcn_mfma_f32_16x16x32_f16(w0.h8, afrag[0], acc, 0, 0, 0);
            acc = __builtin_amdgcn_mfma_f32_16x16x32_f16(w1.h8, afrag[1], acc, 0, 0, 0);
            acc = __builtin_amdgcn_mfma_f32_16x16x32_f16(w2.h8, afrag[2], acc, 0, 0, 0);
            acc = __builtin_amdgcn_mfma_f32_16x16x32_f16(w3.h8, afrag[3], acc, 0, 0, 0);
            const float4 bv = *(const float4*)&bl[c * 16 + quad * 4];
            union { __half2 h2v[2]; float2 f2; } o;
            o.h2v[0] = __floats2half2_rn(acc[0] + bv.x, acc[1] + bv.y);
            o.h2v[1] = __floats2half2_rn(acc[2] + bv.z, acc[3] + bv.w);
            *(float2*)&outl[orow + c * 16 + quad * 4] = o.f2;
        }
        {
            H8 w0, w1, w2, w3;
            w0.f4 = *(const float4*)&WtR[wof +  0];
            w1.f4 = *(const float4*)&WtR[wof + 32];
            w2.f4 = *(const float4*)&WtR[wof + 64];
            w3.f4 = *(const float4*)&WtR[wof + 96];
            f32x4 acc = {0.f, 0.f, 0.f, 0.f};
            acc = __builtin_amdgcn_mfma_f32_16x16x32_f16(w0.h8, afrag[0], acc, 0, 0, 0);
            acc = __builtin_amdgcn_mfma_f32_16x16x32_f16(w1.h8, afrag[1], acc, 0, 0, 0);
            acc = __builtin_amdgcn_mfma_f32_16x16x32_f16(w2.h8, afrag[2], acc, 0, 0, 0);
            acc = __builtin_amdgcn_mfma_f32_16x16x32_f16(w3.h8, afrag[3], acc, 0, 0, 0);
            const float4 bv = *(const float4*)&br[c * 16 + quad * 4];
            union { __half2 h2v[2]; float2 f2; } o;
            o.h2v[0] = __floats2half2_rn(acc[0] + bv.x, acc[1] + bv.y);
            o.h2v[1] = __floats2half2_rn(acc[2] + bv.z, acc[3] + bv.w);
            *(float2*)&outr[orow + c * 16 + quad * 4] = o.f2;
        }
    }
}

// -------------------------------------- per-node online-softmax aggregation
// One wave per node; 16 lanes per edge, 4 edge-groups. CSR padded to x8 with
// src=-1 sentinels: no tail loop. Packed-fp16 dot (pk_add/and/pk_fma + fdot2),
// fp32 online-softmax state, fma_mix accumulation.

template <int C>
static __device__ __forceinline__ void attn_step(
    const __half* __restrict__ xl, int idx, int e, int g, int t,
    const h2 ah[4], const h2 xrh[4], const h2 c06, const h2 c04,
    float& m, float& l, float acc[8])
{
    int s[C];
#pragma unroll
    for (int c = 0; c < C; ++c) s[c] = __shfl(idx, e + 4 * c + g);
    H2x4 r[C];
#pragma unroll
    for (int c = 0; c < C; ++c)
        r[c].f4 = *(const float4*)&xl[(size_t)(s[c] < 0 ? 0 : s[c]) * 128 + t * 8];

    float p[C];
#pragma unroll
    for (int c = 0; c < C; ++c) {
        float pp = 0.f;
#pragma unroll
        for (int j = 0; j < 4; ++j) {
            h2 z = r[c].v[j] + xrh[j];           // v_pk_add_f16
            h2 u = z * c06 + habs2(z) * c04;     // pk_mul + pk_fma (+and)
            pp = FDOT2(u, ah[j], pp);            // v_dot2_f32_f16
        }
        p[c] = pp;
    }
#pragma unroll
    for (int off = 1; off <= 8; off <<= 1)
#pragma unroll
        for (int c = 0; c < C; ++c) p[c] += __shfl_xor(p[c], off, 64);
#pragma unroll
    for (int c = 0; c < C; ++c) if (s[c] < 0) p[c] = NEG_BIG;

    float mn = m;
#pragma unroll
    for (int c = 0; c < C; ++c) mn = fmaxf(mn, p[c]);
    const float sc = __expf(m - mn);
    float w[C], suml = 0.f;
#pragma unroll
    for (int c = 0; c < C; ++c) { w[c] = __expf(p[c] - mn); suml += w[c]; }
    l = fmaf(l, sc, suml);
#pragma unroll
    for (int k = 0; k < 8; ++k) {
        float tt = 0.f;
#pragma unroll
        for (int c = 0; c < C; ++c)
            tt = fmaf(w[c], (float)r[c].h[k], tt);   // v_fma_mix
        acc[k] = fmaf(acc[k], sc, tt);
    }
    m = mn;
}

__global__ __launch_bounds__(256) void attn_k(
    const __half* __restrict__ xl, const __half* __restrict__ xr,
    const int* __restrict__ offs, const int* __restrict__ csr_src,
    const float* __restrict__ att, const float* __restrict__ bias,
    float* __restrict__ out, int n)
{
    const int wid = (blockIdx.x * blockDim.x + threadIdx.x) >> 6;
    const int lane = threadIdx.x & 63;
    if (wid >= n) return;
    const int g = lane >> 4;          // edge group 0..3
    const int t = lane & 15;          // dim slot: dims t*8 .. t*8+7

    const int i0  = offs[wid];
    const int deg = offs[wid + 1] - i0;   // padded to x8

    H2x4 xrr; xrr.f4 = *(const float4*)&xr[(size_t)wid * 128 + t * 8];
    h2 ah[4];
    {
        float4 a0 = *(const float4*)&att[t * 8];
        float4 a1 = *(const float4*)&att[t * 8 + 4];
        ah[0] = h2{(_Float16)a0.x, (_Float16)a0.y};
        ah[1] = h2{(_Float16)a0.z, (_Float16)a0.w};
        ah[2] = h2{(_Float16)a1.x, (_Float16)a1.y};
        ah[3] = h2{(_Float16)a1.z, (_Float16)a1.w};
    }
    const h2 c06 = h2{(_Float16)0.6f, (_Float16)0.6f};
    const h2 c04 = h2{(_Float16)0.4f, (_Float16)0.4f};

    float m = NEG_BIG, l = 0.f, acc[8];
#pragma unroll
    for (int k = 0; k < 8; ++k) acc[k] = 0.f;

    for (int b = 0; b < deg; b += 64) {
        const int nb = min(64, deg - b);        // multiple of 8
        const int idx = (b + lane < deg) ? csr_src[i0 + b + lane] : -1;

        int e = 0;
        for (; e + 16 <= nb; e += 16)
            attn_step<4>(xl, idx, e, g, t, ah, xrr.v, c06, c04, m, l, acc);
        if (e + 8 <= nb)
            attn_step<2>(xl, idx, e, g, t, ah, xrr.v, c06, c04, m, l, acc);
    }

    // merge the 4 group states (butterfly over offsets 16, 32)
#pragma unroll
    for (int off = 16; off <= 32; off <<= 1) {
        const float mo = __shfl_xor(m, off, 64);
        const float lo = __shfl_xor(l, off, 64);
        float ao[8];
#pragma unroll
        for (int k = 0; k < 8; ++k) ao[k] = __shfl_xor(acc[k], off, 64);
        const float mn = fmaxf(m, mo);
        const float sa = __expf(m - mn);         // never-valid groups: weight 0
        const float sb = __expf(mo - mn);
        l = l * sa + lo * sb;
#pragma unroll
        for (int k = 0; k < 8; ++k) acc[k] = acc[k] * sa + ao[k] * sb;
        m = mn;
    }

    if (g == 0) {
        const float inv = 1.0f / fmaxf(l, 1e-16f);
        float o[8];
        const float4 b0 = *(const float4*)&bias[t * 8];
        const float4 b1 = *(const float4*)&bias[t * 8 + 4];
        const float bb[8] = {b0.x, b0.y, b0.z, b0.w, b1.x, b1.y, b1.z, b1.w};
#pragma unroll
        for (int k = 0; k < 8; ++k)
            o[k] = fmaxf(fmaf(acc[k], inv, bb[k]), 0.f);
        float* orow = &out[(size_t)wid * 128 + t * 8];
        *(float4*)&orow[0] = make_float4(o[0], o[1], o[2], o[3]);
        *(float4*)&orow[4] = make_float4(o[4], o[5], o[6], o[7]);
    }
}

// ---------------------------------------------------------------- launcher

extern "C" void kernel_launch(void* const* d_in, const int* in_sizes, int n_in,
                              void* d_out, int out_size, void* d_ws, size_t ws_size,
                              hipStream_t stream) {
    const float* x    = (const float*)d_in[0];
    const int*   ei   = (const int*)d_in[1];
    const float* Wl1  = (const float*)d_in[2];
    const float* bl1  = (const float*)d_in[3];
    const float* Wr1  = (const float*)d_in[4];
    const float* br1  = (const float*)d_in[5];
    const float* att1 = (const float*)d_in[6];
    const float* b1   = (const float*)d_in[7];
    const float* Wl2  = (const float*)d_in[8];
    const float* bl2  = (const float*)d_in[9];
    const float* Wr2  = (const float*)d_in[10];
    const float* br2  = (const float*)d_in[11];
    const float* att2 = (const float*)d_in[12];
    const float* b2   = (const float*)d_in[13];

    const int N = in_sizes[0] / 128;   // 40000
    const int E = in_sizes[1] / 2;     // 640000
    const int* srcp = ei;
    const int* dstp = ei + E;
    const size_t csrCap = (size_t)E + 8 * (size_t)N;   // padded capacity

    char* ws = (char*)d_ws;
    __half* xl     = (__half*)ws; ws += (size_t)N * 128 * 2;
    __half* xr     = (__half*)ws; ws += (size_t)N * 128 * 2;
    int*   csr_src = (int*)ws;    ws += csrCap * 4;
    int*   offs    = (int*)ws;    ws += ((size_t)N + 4) * 4;
    int*   cnt     = (int*)ws;    ws += (size_t)N * 4;
    int*   cursor  = (int*)ws;    ws += (size_t)N * 4;
    int*   partial = (int*)ws;    ws += 1024;
    int*   total   = (int*)ws;    ws += 256;
    __half* Wt1l   = (__half*)ws; ws += 128 * 128 * 2;
    __half* Wt1r   = (__half*)ws; ws += 128 * 128 * 2;
    __half* Wt2l   = (__half*)ws; ws += 128 * 128 * 2;
    __half* Wt2r   = (__half*)ws; ws += 128 * 128 * 2;
    float* h = (float*)d_out;          // layer-1 activations (rewritten by layer 2)

    const int scanBlocks = (N + 255) / 256;       // 157
    const int eBlocks = (E + 255) / 256;          // 2500

    hipMemsetAsync(cnt, 0, (size_t)N * 2 * 4, stream);       // cnt + cursor
    hipMemsetAsync(csr_src, 0xFF, csrCap * 4, stream);       // pad sentinel -1

    // ---- weight prep (one launch) ----
    wprep4<<<dim3(64, 4), 256, 0, stream>>>(Wl1, Wr1, Wl2, Wr2,
                                            Wt1l, Wt1r, Wt2l, Wt2r);

    // ---- CSR by dst, segments padded to x8 (shared by both layers) ----
    count_k<<<eBlocks, 256, 0, stream>>>(dstp, cnt, E);
    scan1<<<scanBlocks, 256, 0, stream>>>(cnt, offs, partial, N);
    scan2<<<1, 256, 0, stream>>>(partial, scanBlocks);
    scan3<<<scanBlocks, 256, 0, stream>>>(offs, partial, N, total);
    scan3b<<<1, 64, 0, stream>>>(offs, cnt, N);
    scatter_k<<<eBlocks, 256, 0, stream>>>(srcp, dstp, offs, cursor, csr_src, E);

    const int nstrips = N / 16;                   // 2500
    const int gemmBlocks = (nstrips + 3) / 4;     // 625 (4 waves/block)
    const int attnBlocks = (N + 3) / 4;           // 10000 (4 waves/block)

    // ---- layer 1 ----
    gemm_mfma<<<gemmBlocks, 256, 0, stream>>>(x, Wt1l, Wt1r, bl1, br1, xl, xr, nstrips);
    attn_k<<<attnBlocks, 256, 0, stream>>>(xl, xr, offs, csr_src, att1, b1, h, N);

    // ---- layer 2 ----
    gemm_mfma<<<gemmBlocks, 256, 0, stream>>>(h, Wt2l, Wt2r, bl2, br2, xl, xr, nstrips);
    attn_k<<<attnBlocks, 256, 0, stream>>>(xl, xr, offs, csr_src, att2, b2,
                                           (float*)d_out, N);
}